// Round 1
// baseline (827.675 us; speedup 1.0000x reference)
//
#include <hip/hip_runtime.h>
#include <math.h>

namespace {

constexpr int T   = 8192;
constexpr int E   = 256;
constexpr int H   = 7168;
constexpr int BM  = 32;    // tokens per block
constexpr int BK  = 32;    // K tile
constexpr int NTH = 1024;  // threads per block
constexpr int PA  = 34;    // sA leading-dim pad (keeps float2 8B-aligned, conflict-free)
constexpr int PW  = 260;   // sW leading-dim pad (keeps float4 16B-aligned)
constexpr float NEG_INF = -1e9f;

__global__ __launch_bounds__(NTH) void gate_fused(
    const float* __restrict__ A,     // [T, H]
    const float* __restrict__ Wt,    // [E, H]
    const float* __restrict__ bias,  // [E]
    float* __restrict__ out)         // [T*8 idx (as float) | T*8 weights]
{
  __shared__ __align__(16) float sA[BK * PA];  // sA[k][m]
  __shared__ __align__(16) float sW[BK * PW];  // sW[k][e]; reused as scores[m][e] in epilogue

  const int tid = threadIdx.x;
  const int m0  = blockIdx.x * BM;

  // compute mapping: 2 tokens x 4 experts per thread
  const int m2 = tid & 15;   // token pair id: tokens 2*m2, 2*m2+1
  const int eq = tid >> 4;   // expert quad id 0..63: experts 4*eq..4*eq+3

  // W staging: each thread loads 2 consecutive float4 (32B) of one expert row
  const int wi  = tid * 2;
  const int we  = wi >> 3;        // expert row 0..255
  const int wkq = wi & 7;         // float4 index within 32-float k-tile (even)
  const size_t wbase = (size_t)we * H + (size_t)wkq * 4;

  // A staging: threads 0..255 load one float4 of one token row
  const int am  = tid >> 3;
  const int akq = tid & 7;
  const size_t abase = (size_t)(m0 + am) * H + (size_t)akq * 4;

  float4 rw0, rw1, ra;
  // prologue prefetch (k0 = 0)
  rw0 = *(const float4*)&Wt[wbase];
  rw1 = *(const float4*)&Wt[wbase + 4];
  if (tid < 256) ra = *(const float4*)&A[abase];

  float acc[2][4] = {{0.f, 0.f, 0.f, 0.f}, {0.f, 0.f, 0.f, 0.f}};

  for (int k0 = 0; k0 < H; k0 += BK) {
    // ---- write staged registers to LDS (transposed: k-major) ----
    sW[(wkq * 4 + 0) * PW + we] = rw0.x;
    sW[(wkq * 4 + 1) * PW + we] = rw0.y;
    sW[(wkq * 4 + 2) * PW + we] = rw0.z;
    sW[(wkq * 4 + 3) * PW + we] = rw0.w;
    sW[(wkq * 4 + 4) * PW + we] = rw1.x;
    sW[(wkq * 4 + 5) * PW + we] = rw1.y;
    sW[(wkq * 4 + 6) * PW + we] = rw1.z;
    sW[(wkq * 4 + 7) * PW + we] = rw1.w;
    if (tid < 256) {
      sA[(akq * 4 + 0) * PA + am] = ra.x;
      sA[(akq * 4 + 1) * PA + am] = ra.y;
      sA[(akq * 4 + 2) * PA + am] = ra.z;
      sA[(akq * 4 + 3) * PA + am] = ra.w;
    }
    __syncthreads();

    // ---- prefetch next K tile into registers (hides global latency under FMAs) ----
    if (k0 + BK < H) {
      rw0 = *(const float4*)&Wt[wbase + (size_t)(k0 + BK)];
      rw1 = *(const float4*)&Wt[wbase + (size_t)(k0 + BK) + 4];
      if (tid < 256) ra = *(const float4*)&A[abase + (size_t)(k0 + BK)];
    }

    // ---- compute: 8 FMA per k ----
#pragma unroll
    for (int k = 0; k < BK; ++k) {
      const float2 av = *(const float2*)&sA[k * PA + m2 * 2];
      const float4 wv = *(const float4*)&sW[k * PW + eq * 4];
      acc[0][0] = fmaf(av.x, wv.x, acc[0][0]);
      acc[0][1] = fmaf(av.x, wv.y, acc[0][1]);
      acc[0][2] = fmaf(av.x, wv.z, acc[0][2]);
      acc[0][3] = fmaf(av.x, wv.w, acc[0][3]);
      acc[1][0] = fmaf(av.y, wv.x, acc[1][0]);
      acc[1][1] = fmaf(av.y, wv.y, acc[1][1]);
      acc[1][2] = fmaf(av.y, wv.z, acc[1][2]);
      acc[1][3] = fmaf(av.y, wv.w, acc[1][3]);
    }
    __syncthreads();
  }

  // ---- epilogue: sigmoid -> scores in LDS (reuse sW as scores[m][e], stride PW) ----
#pragma unroll
  for (int tk = 0; tk < 2; ++tk) {
    const int m = 2 * m2 + tk;
#pragma unroll
    for (int j = 0; j < 4; ++j) {
      const float s = 1.f / (1.f + expf(-acc[tk][j]));
      sW[m * PW + eq * 4 + j] = s;
    }
  }
  __syncthreads();

  // ---- routing: one wave handles 2 tokens ----
  const int lane = tid & 63;
  const int wid  = tid >> 6;  // 0..15
  const float4 b4 = ((const float4*)bias)[lane];

  for (int tk = 0; tk < 2; ++tk) {
    const int m = wid * 2 + tk;
    const float4 s4 = *(const float4*)&sW[m * PW + lane * 4];
    const float su0 = s4.x, su1 = s4.y, su2 = s4.z, su3 = s4.w;
    float sc0 = s4.x + b4.x;
    float sc1 = s4.y + b4.y;
    float sc2 = s4.z + b4.z;
    float sc3 = s4.w + b4.w;

    // per-lane top2 of 4 (biased scores)
    float t1, t2;
    {
      const float p1 = fmaxf(sc0, sc1), p2 = fminf(sc0, sc1);
      const float q1 = fmaxf(sc2, sc3), q2 = fminf(sc2, sc3);
      t1 = fmaxf(p1, q1);
      t2 = fmaxf(fminf(p1, q1), fmaxf(p2, q2));
    }
    // reduce top2 across the 8 lanes of this group (experts e/32)
#pragma unroll
    for (int d = 1; d < 8; d <<= 1) {
      const float o1 = __shfl_xor(t1, d);
      const float o2 = __shfl_xor(t2, d);
      const float n1 = fmaxf(t1, o1);
      const float n2 = fmaxf(fminf(t1, o1), fmaxf(t2, o2));
      t1 = n1; t2 = n2;
    }
    const float gs = t1 + t2;  // this lane's group score

    // rank my group among all 8 (ties -> lower group index wins)
    const int gme = lane >> 3;
    int rank = 0;
#pragma unroll
    for (int g = 0; g < 8; ++g) {
      const float og = __shfl(gs, g * 8);
      rank += (og > gs) || (og == gs && g < gme);
    }
    const bool keep = (rank < 4);

    float mk0 = keep ? sc0 : NEG_INF;
    float mk1 = keep ? sc1 : NEG_INF;
    float mk2 = keep ? sc2 : NEG_INF;
    float mk3 = keep ? sc3 : NEG_INF;

    float wvals[8];
    int   widx[8];
    float wsum = 0.f;

#pragma unroll
    for (int j = 0; j < 8; ++j) {
      // per-lane argmax of 4 (ties -> lower slot = lower expert index)
      float bv = mk0; int bq = 0;
      if (mk1 > bv) { bv = mk1; bq = 1; }
      if (mk2 > bv) { bv = mk2; bq = 2; }
      if (mk3 > bv) { bv = mk3; bq = 3; }
      int bidx = lane * 4 + bq;
      // wave argmax with (value desc, index asc) tie-break -> matches jax.lax.top_k order
#pragma unroll
      for (int d = 1; d < 64; d <<= 1) {
        const float ov = __shfl_xor(bv, d);
        const int   oi = __shfl_xor(bidx, d);
        if (ov > bv || (ov == bv && oi < bidx)) { bv = ov; bidx = oi; }
      }
      const int ol = bidx >> 2;
      const int oq = bidx & 3;
      // weight = UNbiased sigmoid score at winning index
      const float sv = (oq == 0) ? su0 : (oq == 1) ? su1 : (oq == 2) ? su2 : su3;
      const float wj = __shfl(sv, ol);
      // remove winner from its owner lane (static indices only)
      if (lane == ol) {
        if (oq == 0) mk0 = -3.4e38f;
        else if (oq == 1) mk1 = -3.4e38f;
        else if (oq == 2) mk2 = -3.4e38f;
        else mk3 = -3.4e38f;
      }
      wsum += wj;
      wvals[j] = wj;
      widx[j]  = bidx;
    }

    if (lane == 0) {
      const float scale = 2.5f / (wsum + 1e-20f);
      const size_t row = (size_t)(m0 + m) * 8;
#pragma unroll
      for (int j = 0; j < 8; ++j) {
        out[row + j]                 = (float)widx[j];      // topk_idx as float value
        out[(size_t)T * 8 + row + j] = wvals[j] * scale;    // topk_w
      }
    }
  }
}

}  // namespace

extern "C" void kernel_launch(void* const* d_in, const int* in_sizes, int n_in,
                              void* d_out, int out_size, void* d_ws, size_t ws_size,
                              hipStream_t stream) {
  const float* A    = (const float*)d_in[0];
  const float* W    = (const float*)d_in[1];
  const float* bias = (const float*)d_in[2];
  float* out = (float*)d_out;

  dim3 grid(T / BM);   // 256 blocks, ~1 per CU
  dim3 block(NTH);
  hipLaunchKernelGGL(gate_fused, grid, block, 0, stream, A, W, bias, out);
}